// Round 1
// 208.378 us; speedup vs baseline: 1.0165x; 1.0165x over previous
//
#include <hip/hip_runtime.h>
#include <hip/hip_bf16.h>
#include <stdint.h>

typedef unsigned short u16;
typedef __attribute__((ext_vector_type(8))) short short8;
typedef __attribute__((ext_vector_type(4))) float float4v;
typedef __attribute__((ext_vector_type(2))) _Float16 v2h;

// RNE float->bf16
__device__ __forceinline__ u16 f2bf(float x) {
    union { float f; unsigned int u; } v; v.f = x;
    unsigned int r = v.u + 0x7fffu + ((v.u >> 16) & 1u);
    return (u16)(r >> 16);
}

__device__ __forceinline__ void ld_g2l16(const void* g, void* l) {
    __builtin_amdgcn_global_load_lds(
        (const __attribute__((address_space(1))) void*)g,
        (__attribute__((address_space(3))) void*)l, 16, 0, 0);
}

// packed fp16 dot-accumulate: s += a.x*b.x + a.y*b.y (fp32 acc)
__device__ __forceinline__ float dot2acc(v2h a, v2h b, float s) {
#if __has_builtin(__builtin_amdgcn_fdot2)
    return __builtin_amdgcn_fdot2(a, b, s, false);
#else
    return fmaf((float)a[0], (float)b[0], fmaf((float)a[1], (float)b[1], s));
#endif
}

// ---------------- Pass 0: pack W1 into B-frag layout (tiny) ----------------------
// W1pack[kc][t][lane][j] = W1[kc*32 + (lane>>4)*8 + j][t*16 + (lane&15)]
__global__ __launch_bounds__(256) void w1_pack(
    const float* __restrict__ W1, u16* __restrict__ w1p)
{
    int w = blockIdx.x * 256 + threadIdx.x;   // 0..4095
    int lanep = w & 63, t = (w >> 6) & 7, kc = w >> 9;
    short8 o;
#pragma unroll
    for (int j = 0; j < 8; ++j) {
        int k = kc * 32 + (lanep >> 4) * 8 + j;
        int n = t * 16 + (lanep & 15);
        o[j] = (short)f2bf(W1[k * 128 + n]);
    }
    *(short8*)(w1p + (size_t)w * 8) = o;
}

// ---------------- Pass 1: dense GEMMs U = zs@W1a + b1, V = zt@W1b (fp16 out) -----
// Block = 256 thr, 128x128 output tile, K=128 single shot.
// A staged fp32->bf16 through VGPRs into LDS with per-row XOR chunk swizzle
// (phys chunk q = c ^ (r&15)): MFMA-side ds_read_b128 is 2-way (free).
// B = W1 half in frag layout from w1p (flat 32KB, conflict-free frag reads).
// Output stored as fp16 (finer mantissa than bf16 at |x|<=8; enables packed
// math in edge_out).
// UNCHANGED this round (A/B isolation of the edge_out scheduling change).
__global__ __launch_bounds__(256) void uv_gemm(
    const float* __restrict__ zs, const float* __restrict__ zt,
    const u16* __restrict__ w1p, const float* __restrict__ b1,
    u16* __restrict__ U, u16* __restrict__ V,
    int M1, int M2, int nU)
{
    __shared__ u16 Alds[16384];   // 32 KB: 128 rows x 128 K (swizzled chunks)
    __shared__ u16 Blds[16384];   // 32 KB: 32 frags of this W1 half

    const int tid = threadIdx.x, wave = tid >> 6, lane = tid & 63;
    const int m15 = lane & 15, quad = lane >> 4;
    const bool isV = (int)blockIdx.x >= nU;
    const float* zsrc = isV ? zt : zs;
    u16* dst = isV ? V : U;
    const int row0 = (isV ? ((int)blockIdx.x - nU) : (int)blockIdx.x) * 128;
    const int M = isV ? M2 : M1;
    const int nrows = (M - row0) < 128 ? (M - row0) : 128;

    // stage B half (32 KB flat): frag f local = kc_local*8+t
    const u16* wsrc = w1p + (isV ? 16384 : 0);
#pragma unroll
    for (int it = 0; it < 8; ++it) {
        int off = (wave * 8 + it) * 1024;
        ld_g2l16((const char*)wsrc + off + lane * 16, (char*)Blds + off);
    }

    // stage A: 128 rows x 16 chunks(16B); lane = (row-in-quad)*16 + phys-chunk q
#pragma unroll
    for (int it = 0; it < 8; ++it) {
        int r = it * 16 + wave * 4 + (lane >> 4);
        int q = lane & 15;
        int c = q ^ (r & 15);                     // logical chunk to fetch
        int rr = r < nrows ? r : (nrows - 1);
        const float4* src = (const float4*)(zsrc + (size_t)(row0 + rr) * 128 + c * 8);
        float4 x = src[0], y = src[1];
        short8 o;
        o[0] = (short)f2bf(x.x); o[1] = (short)f2bf(x.y);
        o[2] = (short)f2bf(x.z); o[3] = (short)f2bf(x.w);
        o[4] = (short)f2bf(y.x); o[5] = (short)f2bf(y.y);
        o[6] = (short)f2bf(y.z); o[7] = (short)f2bf(y.w);
        *(short8*)((char*)Alds + r * 256 + q * 16) = o;
    }

    __builtin_amdgcn_s_waitcnt(0);
    __syncthreads();

    // MFMA: wave owns rows [wave*32, +32) x all 128 n
    float4v acc[2][8];
#pragma unroll
    for (int a = 0; a < 2; ++a)
#pragma unroll
        for (int b = 0; b < 8; ++b)
            acc[a][b] = (float4v){0.f, 0.f, 0.f, 0.f};

#pragma unroll
    for (int kc = 0; kc < 4; ++kc) {
        short8 Af[2];
#pragma unroll
        for (int mtl = 0; mtl < 2; ++mtl) {
            int r = wave * 32 + mtl * 16 + m15;
            int c = kc * 4 + quad;
            int q = c ^ (r & 15);
            Af[mtl] = *(const short8*)((const char*)Alds + r * 256 + q * 16);
        }
#pragma unroll
        for (int t = 0; t < 8; ++t) {
            short8 Bf = *(const short8*)((const char*)Blds + (kc * 8 + t) * 1024 + lane * 16);
#pragma unroll
            for (int mtl = 0; mtl < 2; ++mtl)
                acc[mtl][t] = __builtin_amdgcn_mfma_f32_16x16x32_bf16(
                    Af[mtl], Bf, acc[mtl][t], 0, 0, 0);
        }
    }

    // epilogue: +b1 (U only), round to fp16, store. C/D: col=t*16+m15, row=quad*4+r
#pragma unroll
    for (int t = 0; t < 8; ++t) {
        float bv = isV ? 0.f : b1[t * 16 + m15];
#pragma unroll
        for (int mtl = 0; mtl < 2; ++mtl) {
#pragma unroll
            for (int r = 0; r < 4; ++r) {
                int rr = wave * 32 + mtl * 16 + quad * 4 + r;
                if (rr < nrows) {
                    _Float16 h = (_Float16)(acc[mtl][t][r] + bv);
                    union { _Float16 h; u16 u; } cv; cv.h = h;
                    dst[(size_t)(row0 + rr) * 128 + t * 16 + m15] = cv.u;
                }
            }
        }
    }
}

// ---------------- Pass 2: streaming edge decode: relu(U[row]+V[col]).W2 + b2 -----
// 16 lanes per edge (lane m15 owns features [m15*8, m15*8+8)); 128 edges/block.
//
// ROUND-1 CHANGE: previous build had VGPR_Count=40 — the compiler had collapsed
// the intended 16-gather batch into a ~2-deep load->use pipeline (only ~4 loads
// in flight/thread), leaving the kernel latency-bound at 3.5 TB/s. Now the
// schedule is pinned with sched_barrier(0) fences:
//   [16 index loads] | fence | [16 payload gathers] | fence | [consume]
// so all 16 gathers stay in flight per thread (VGPR ~100, still 4 waves/SIMD).
__global__ __launch_bounds__(256) void edge_out(
    const u16* __restrict__ U, const u16* __restrict__ V,
    const int* __restrict__ row, const int* __restrict__ col,
    const float* __restrict__ W2, const float* __restrict__ b2,
    float* __restrict__ out, int E)
{
    const int tid = threadIdx.x, m15 = tid & 15, g = tid >> 4;  // 16 groups
    v2h w2h[4];
#pragma unroll
    for (int j = 0; j < 4; ++j) {
        w2h[j][0] = (_Float16)W2[m15 * 8 + 2 * j];
        w2h[j][1] = (_Float16)W2[m15 * 8 + 2 * j + 1];
    }
    const float b2v = b2[0];
    const v2h zero2 = (v2h){(_Float16)0.f, (_Float16)0.f};
    const int e0 = blockIdx.x * 128;

    // Phase 1: all 16 index loads issued back-to-back (coalesced, broadcast
    // across the 16 lanes of each group).
    int re[8], ce[8];
#pragma unroll
    for (int it = 0; it < 8; ++it) {
        int e = e0 + it * 16 + g;
        int ec = e < E ? e : E - 1;
        re[it] = row[ec];
        ce[it] = col[ec];
    }
    __builtin_amdgcn_sched_barrier(0);

    // Phase 2: all 16 payload gathers issued back-to-back (16B each).
    uint4 uu[8], vv[8];
#pragma unroll
    for (int it = 0; it < 8; ++it) {
        uu[it] = *(const uint4*)(U + (size_t)(unsigned)re[it] * 128 + m15 * 8);
        vv[it] = *(const uint4*)(V + (size_t)(unsigned)ce[it] * 128 + m15 * 8);
    }
    __builtin_amdgcn_sched_barrier(0);

    // Phase 3: consume in issue order (progressive vmcnt waits).
#pragma unroll
    for (int it = 0; it < 8; ++it) {
        float s = 0.f;
        const v2h* uw = (const v2h*)&uu[it];
        const v2h* vw = (const v2h*)&vv[it];
#pragma unroll
        for (int j = 0; j < 4; ++j) {
            v2h h = uw[j] + vw[j];                       // v_pk_add_f16
            h = __builtin_elementwise_max(h, zero2);     // v_pk_max_f16 (relu)
            s = dot2acc(h, w2h[j], s);                   // v_dot2_f32_f16
        }
        s += __shfl_xor(s, 1);
        s += __shfl_xor(s, 2);
        s += __shfl_xor(s, 4);
        s += __shfl_xor(s, 8);
        int e = e0 + it * 16 + g;
        if (m15 == 0 && e < E) out[e] = s + b2v;
    }
}

// ---------------- Fallback (fp32, slow but correct) if workspace too small -------
__global__ __launch_bounds__(256) void edge_mlp_naive(
    const float* __restrict__ zs, const float* __restrict__ zt,
    const int* __restrict__ row, const int* __restrict__ col,
    const float* __restrict__ W1, const float* __restrict__ b1,
    const float* __restrict__ W2, const float* __restrict__ b2,
    float* __restrict__ out, int E)
{
    __shared__ float zr[4][256];
    int wave = threadIdx.x >> 6, lane = threadIdx.x & 63;
    int e = blockIdx.x * 4 + wave;
    int ec = e < E ? e : E - 1;
    const float* a = zs + (size_t)row[ec] * 128;
    const float* bb = zt + (size_t)col[ec] * 128;
    zr[wave][lane] = a[lane];
    zr[wave][64 + lane] = a[64 + lane];
    zr[wave][128 + lane] = bb[lane];
    zr[wave][192 + lane] = bb[64 + lane];
    __syncthreads();
    float h0 = b1[lane], h1 = b1[64 + lane];
    for (int k = 0; k < 256; ++k) {
        float zk = zr[wave][k];
        h0 = fmaf(zk, W1[k * 128 + lane], h0);
        h1 = fmaf(zk, W1[k * 128 + 64 + lane], h1);
    }
    h0 = h0 > 0.f ? h0 : 0.f;
    h1 = h1 > 0.f ? h1 : 0.f;
    float s = fmaf(h0, W2[lane], h1 * W2[64 + lane]);
    for (int m = 1; m < 64; m <<= 1) s += __shfl_xor(s, m);
    if (lane == 0 && e < E) out[e] = s + b2[0];
}

extern "C" void kernel_launch(void* const* d_in, const int* in_sizes, int n_in,
                              void* d_out, int out_size, void* d_ws, size_t ws_size,
                              hipStream_t stream) {
    const float* zs = (const float*)d_in[0];
    const float* zt = (const float*)d_in[1];
    const int*  row = (const int*)d_in[2];
    const int*  col = (const int*)d_in[3];
    const float* W1 = (const float*)d_in[4];
    const float* b1 = (const float*)d_in[5];
    const float* W2 = (const float*)d_in[6];
    const float* b2 = (const float*)d_in[7];
    float* out = (float*)d_out;

    const int nzs = in_sizes[0];       // 12,800,000 (100K x 128)
    const int nzt = in_sizes[1];       // 6,400,000  (50K x 128)
    const int E   = in_sizes[2];       // 1,000,000
    const int M1  = nzs / 128;
    const int M2  = nzt / 128;

    const size_t need = ((size_t)nzs + (size_t)nzt + 32768) * 2;
    if (ws_size < need) {
        int nb = (E + 3) / 4;
        edge_mlp_naive<<<nb, 256, 0, stream>>>(zs, zt, row, col, W1, b1, W2, b2, out, E);
        return;
    }

    u16* U   = (u16*)d_ws;             // M1 x 128 fp16
    u16* V   = U + (size_t)nzs;        // M2 x 128 fp16
    u16* w1p = V + (size_t)nzt;        // 64 KB packed W1 (bf16 frags)

    w1_pack<<<16, 256, 0, stream>>>(W1, w1p);

    const int nU = (M1 + 127) / 128;
    const int nV = (M2 + 127) / 128;
    uv_gemm<<<nU + nV, 256, 0, stream>>>(zs, zt, w1p, b1, U, V, M1, M2, nU);

    edge_out<<<(E + 127) / 128, 256, 0, stream>>>(U, V, row, col, W2, b2, out, E);
}

// Round 2
// 189.837 us; speedup vs baseline: 1.1158x; 1.0977x over previous
//
#include <hip/hip_runtime.h>
#include <hip/hip_bf16.h>
#include <stdint.h>

typedef unsigned short u16;
typedef __attribute__((ext_vector_type(8))) short short8;
typedef __attribute__((ext_vector_type(4))) float float4v;

// RNE float->bf16
__device__ __forceinline__ u16 f2bf(float x) {
    union { float f; unsigned int u; } v; v.f = x;
    unsigned int r = v.u + 0x7fffu + ((v.u >> 16) & 1u);
    return (u16)(r >> 16);
}

__device__ __forceinline__ void ld_g2l16(const void* g, void* l) {
    __builtin_amdgcn_global_load_lds(
        (const __attribute__((address_space(1))) void*)g,
        (__attribute__((address_space(3))) void*)l, 16, 0, 0);
}

// sign-extended byte j (j must be compile-time after unroll) of packed word w
__device__ __forceinline__ float sbyte_f(int w, int j) {
    return (float)((w << (24 - 8 * j)) >> 24);     // v_bfe_i32 + v_cvt_f32_i32
}

// ---------------- Pass 0: pack W1 into B-frag layout (tiny) ----------------------
// W1pack[kc][t][lane][j] = W1[kc*32 + (lane>>4)*8 + j][t*16 + (lane&15)]
__global__ __launch_bounds__(256) void w1_pack(
    const float* __restrict__ W1, u16* __restrict__ w1p)
{
    int w = blockIdx.x * 256 + threadIdx.x;   // 0..4095
    int lanep = w & 63, t = (w >> 6) & 7, kc = w >> 9;
    short8 o;
#pragma unroll
    for (int j = 0; j < 8; ++j) {
        int k = kc * 32 + (lanep >> 4) * 8 + j;
        int n = t * 16 + (lanep & 15);
        o[j] = (short)f2bf(W1[k * 128 + n]);
    }
    *(short8*)(w1p + (size_t)w * 8) = o;
}

// ---------------- Pass 1: dense GEMMs U = zs@W1a + b1, V = zt@W1b ----------------
// Main loop unchanged from round 1 (bf16 MFMA, swizzled LDS A, frag-layout B).
// ROUND-2 CHANGE (epilogue): output is now int8 with a per-row symmetric scale
// (s = rowmax/127). Gaussian rows => int8-per-row RMS err ~0.5% of rowmax, 4x
// better than fp8-e4m3 at equal bytes. Halves uv_gemm write traffic and halves
// edge_out's gather payload (the measured wall).
__global__ __launch_bounds__(256) void uv_gemm(
    const float* __restrict__ zs, const float* __restrict__ zt,
    const u16* __restrict__ w1p, const float* __restrict__ b1,
    char* __restrict__ U8, char* __restrict__ V8,
    float* __restrict__ su, float* __restrict__ sv,
    int M1, int M2, int nU)
{
    __shared__ u16 Alds[16384];   // 32 KB: 128 rows x 128 K (swizzled chunks)
    __shared__ u16 Blds[16384];   // 32 KB: 32 frags of this W1 half

    const int tid = threadIdx.x, wave = tid >> 6, lane = tid & 63;
    const int m15 = lane & 15, quad = lane >> 4;
    const bool isV = (int)blockIdx.x >= nU;
    const float* zsrc = isV ? zt : zs;
    char* dst = isV ? V8 : U8;
    float* sdst = isV ? sv : su;
    const int row0 = (isV ? ((int)blockIdx.x - nU) : (int)blockIdx.x) * 128;
    const int M = isV ? M2 : M1;
    const int nrows = (M - row0) < 128 ? (M - row0) : 128;

    // stage B half (32 KB flat): frag f local = kc_local*8+t
    const u16* wsrc = w1p + (isV ? 16384 : 0);
#pragma unroll
    for (int it = 0; it < 8; ++it) {
        int off = (wave * 8 + it) * 1024;
        ld_g2l16((const char*)wsrc + off + lane * 16, (char*)Blds + off);
    }

    // stage A: 128 rows x 16 chunks(16B); lane = (row-in-quad)*16 + phys-chunk q
#pragma unroll
    for (int it = 0; it < 8; ++it) {
        int r = it * 16 + wave * 4 + (lane >> 4);
        int q = lane & 15;
        int c = q ^ (r & 15);                     // logical chunk to fetch
        int rr = r < nrows ? r : (nrows - 1);
        const float4* src = (const float4*)(zsrc + (size_t)(row0 + rr) * 128 + c * 8);
        float4 x = src[0], y = src[1];
        short8 o;
        o[0] = (short)f2bf(x.x); o[1] = (short)f2bf(x.y);
        o[2] = (short)f2bf(x.z); o[3] = (short)f2bf(x.w);
        o[4] = (short)f2bf(y.x); o[5] = (short)f2bf(y.y);
        o[6] = (short)f2bf(y.z); o[7] = (short)f2bf(y.w);
        *(short8*)((char*)Alds + r * 256 + q * 16) = o;
    }

    __builtin_amdgcn_s_waitcnt(0);
    __syncthreads();

    // MFMA: wave owns rows [wave*32, +32) x all 128 n
    float4v acc[2][8];
#pragma unroll
    for (int a = 0; a < 2; ++a)
#pragma unroll
        for (int b = 0; b < 8; ++b)
            acc[a][b] = (float4v){0.f, 0.f, 0.f, 0.f};

#pragma unroll
    for (int kc = 0; kc < 4; ++kc) {
        short8 Af[2];
#pragma unroll
        for (int mtl = 0; mtl < 2; ++mtl) {
            int r = wave * 32 + mtl * 16 + m15;
            int c = kc * 4 + quad;
            int q = c ^ (r & 15);
            Af[mtl] = *(const short8*)((const char*)Alds + r * 256 + q * 16);
        }
#pragma unroll
        for (int t = 0; t < 8; ++t) {
            short8 Bf = *(const short8*)((const char*)Blds + (kc * 8 + t) * 1024 + lane * 16);
#pragma unroll
            for (int mtl = 0; mtl < 2; ++mtl)
                acc[mtl][t] = __builtin_amdgcn_mfma_f32_16x16x32_bf16(
                    Af[mtl], Bf, acc[mtl][t], 0, 0, 0);
        }
    }

    // epilogue: +b1 (U only), per-row absmax -> int8 quantize + scale store.
    // C/D frag: col = t*16 + m15, row = wave*32 + mtl*16 + quad*4 + r
    float b1v[8];
#pragma unroll
    for (int t = 0; t < 8; ++t) b1v[t] = isV ? 0.f : b1[t * 16 + m15];

#pragma unroll
    for (int mtl = 0; mtl < 2; ++mtl) {
#pragma unroll
        for (int r = 0; r < 4; ++r) {
            const int rr = wave * 32 + mtl * 16 + quad * 4 + r;
            float vals[8];
            float vmax = 0.f;
#pragma unroll
            for (int t = 0; t < 8; ++t) {
                float x = acc[mtl][t][r] + b1v[t];
                vals[t] = x;
                vmax = fmaxf(vmax, fabsf(x));
            }
            // row-wide absmax across the 16 lanes sharing this row (m15 bits)
            vmax = fmaxf(vmax, __shfl_xor(vmax, 1));
            vmax = fmaxf(vmax, __shfl_xor(vmax, 2));
            vmax = fmaxf(vmax, __shfl_xor(vmax, 4));
            vmax = fmaxf(vmax, __shfl_xor(vmax, 8));
            const float scl = vmax * (1.f / 127.f);
            const float rs = vmax > 0.f ? 127.f / vmax : 0.f;
            if (rr < nrows) {
                if (m15 == 0) sdst[row0 + rr] = scl;
#pragma unroll
                for (int t = 0; t < 8; ++t) {
                    int q = __float2int_rn(vals[t] * rs);
                    q = q > 127 ? 127 : (q < -127 ? -127 : q);
                    dst[(size_t)(row0 + rr) * 128 + t * 16 + m15] = (char)q;
                }
            }
        }
    }
}

// ---------------- Pass 2: streaming edge decode: relu(su*qU[row]+sv*qV[col]).W2 --
// 16 lanes per edge (lane m15 owns features [m15*8, m15*8+8)); 128 edges/block.
// Gather payload per edge: 128B qU + 128B qV + 2 scales (264B, was 512B fp16).
__global__ __launch_bounds__(256) void edge_out(
    const char* __restrict__ U8, const char* __restrict__ V8,
    const float* __restrict__ su, const float* __restrict__ sv,
    const int* __restrict__ row, const int* __restrict__ col,
    const float* __restrict__ W2, const float* __restrict__ b2,
    float* __restrict__ out, int E)
{
    const int tid = threadIdx.x, m15 = tid & 15, g = tid >> 4;  // 16 groups
    float w2f[8];
#pragma unroll
    for (int j = 0; j < 8; ++j) w2f[j] = W2[m15 * 8 + j];
    const float b2v = b2[0];
    const int e0 = blockIdx.x * 128;

    // Phase 1: index loads (broadcast within each 16-lane group).
    int re[8], ce[8];
#pragma unroll
    for (int it = 0; it < 8; ++it) {
        int e = e0 + it * 16 + g;
        int ec = e < E ? e : E - 1;
        re[it] = row[ec];
        ce[it] = col[ec];
    }
    __builtin_amdgcn_sched_barrier(0);

    // Phase 2: payload gathers (8B int8 chunk per lane per side) + scales.
    uint2 qu[8], qv[8];
    float fsu[8], fsv[8];
#pragma unroll
    for (int it = 0; it < 8; ++it) {
        qu[it] = *(const uint2*)(U8 + (size_t)(unsigned)re[it] * 128 + m15 * 8);
        qv[it] = *(const uint2*)(V8 + (size_t)(unsigned)ce[it] * 128 + m15 * 8);
        fsu[it] = su[re[it]];
        fsv[it] = sv[ce[it]];
    }
    __builtin_amdgcn_sched_barrier(0);

    // Phase 3: dequant + relu + dot, consume in issue order.
#pragma unroll
    for (int it = 0; it < 8; ++it) {
        const float a = fsu[it], b = fsv[it];
        const int u0 = (int)qu[it].x, u1 = (int)qu[it].y;
        const int v0 = (int)qv[it].x, v1 = (int)qv[it].y;
        float s = 0.f;
#pragma unroll
        for (int j = 0; j < 4; ++j) {
            float h0 = fmaf(a, sbyte_f(u0, j), b * sbyte_f(v0, j));
            h0 = fmaxf(h0, 0.f);
            s = fmaf(h0, w2f[j], s);
            float h1 = fmaf(a, sbyte_f(u1, j), b * sbyte_f(v1, j));
            h1 = fmaxf(h1, 0.f);
            s = fmaf(h1, w2f[4 + j], s);
        }
        s += __shfl_xor(s, 1);
        s += __shfl_xor(s, 2);
        s += __shfl_xor(s, 4);
        s += __shfl_xor(s, 8);
        int e = e0 + it * 16 + g;
        if (m15 == 0 && e < E) out[e] = s + b2v;
    }
}

// ---------------- Fallback (fp32, slow but correct) if workspace too small -------
__global__ __launch_bounds__(256) void edge_mlp_naive(
    const float* __restrict__ zs, const float* __restrict__ zt,
    const int* __restrict__ row, const int* __restrict__ col,
    const float* __restrict__ W1, const float* __restrict__ b1,
    const float* __restrict__ W2, const float* __restrict__ b2,
    float* __restrict__ out, int E)
{
    __shared__ float zr[4][256];
    int wave = threadIdx.x >> 6, lane = threadIdx.x & 63;
    int e = blockIdx.x * 4 + wave;
    int ec = e < E ? e : E - 1;
    const float* a = zs + (size_t)row[ec] * 128;
    const float* bb = zt + (size_t)col[ec] * 128;
    zr[wave][lane] = a[lane];
    zr[wave][64 + lane] = a[64 + lane];
    zr[wave][128 + lane] = bb[lane];
    zr[wave][192 + lane] = bb[64 + lane];
    __syncthreads();
    float h0 = b1[lane], h1 = b1[64 + lane];
    for (int k = 0; k < 256; ++k) {
        float zk = zr[wave][k];
        h0 = fmaf(zk, W1[k * 128 + lane], h0);
        h1 = fmaf(zk, W1[k * 128 + 64 + lane], h1);
    }
    h0 = h0 > 0.f ? h0 : 0.f;
    h1 = h1 > 0.f ? h1 : 0.f;
    float s = fmaf(h0, W2[lane], h1 * W2[64 + lane]);
    for (int m = 1; m < 64; m <<= 1) s += __shfl_xor(s, m);
    if (lane == 0 && e < E) out[e] = s + b2[0];
}

extern "C" void kernel_launch(void* const* d_in, const int* in_sizes, int n_in,
                              void* d_out, int out_size, void* d_ws, size_t ws_size,
                              hipStream_t stream) {
    const float* zs = (const float*)d_in[0];
    const float* zt = (const float*)d_in[1];
    const int*  row = (const int*)d_in[2];
    const int*  col = (const int*)d_in[3];
    const float* W1 = (const float*)d_in[4];
    const float* b1 = (const float*)d_in[5];
    const float* W2 = (const float*)d_in[6];
    const float* b2 = (const float*)d_in[7];
    float* out = (float*)d_out;

    const int nzs = in_sizes[0];       // 12,800,000 (100K x 128)
    const int nzt = in_sizes[1];       // 6,400,000  (50K x 128)
    const int E   = in_sizes[2];       // 1,000,000
    const int M1  = nzs / 128;
    const int M2  = nzt / 128;

    // workspace layout: [su f32 M1][sv f32 M2][w1p u16 32768][U8 nzs][V8 nzt]
    const size_t need = (size_t)(M1 + M2) * 4 + 65536 + (size_t)nzs + (size_t)nzt;
    if (ws_size < need) {
        int nb = (E + 3) / 4;
        edge_mlp_naive<<<nb, 256, 0, stream>>>(zs, zt, row, col, W1, b1, W2, b2, out, E);
        return;
    }

    float* su = (float*)d_ws;
    float* sv = su + M1;
    u16* w1p  = (u16*)(sv + M2);
    char* U8  = (char*)(w1p + 32768);
    char* V8  = U8 + (size_t)nzs;

    w1_pack<<<16, 256, 0, stream>>>(W1, w1p);

    const int nU = (M1 + 127) / 128;
    const int nV = (M2 + 127) / 128;
    uv_gemm<<<nU + nV, 256, 0, stream>>>(zs, zt, w1p, b1, U8, V8, su, sv, M1, M2, nU);

    edge_out<<<(E + 127) / 128, 256, 0, stream>>>(U8, V8, su, sv, row, col, W2, b2, out, E);
}

// Round 3
// 179.473 us; speedup vs baseline: 1.1802x; 1.0577x over previous
//
#include <hip/hip_runtime.h>
#include <hip/hip_bf16.h>
#include <stdint.h>

typedef unsigned short u16;
typedef unsigned long long u64;
typedef __attribute__((ext_vector_type(8))) short short8;
typedef __attribute__((ext_vector_type(4))) float float4v;

// RNE float->bf16
__device__ __forceinline__ u16 f2bf(float x) {
    union { float f; unsigned int u; } v; v.f = x;
    unsigned int r = v.u + 0x7fffu + ((v.u >> 16) & 1u);
    return (u16)(r >> 16);
}

__device__ __forceinline__ void ld_g2l16(const void* g, void* l) {
    __builtin_amdgcn_global_load_lds(
        (const __attribute__((address_space(1))) void*)g,
        (__attribute__((address_space(3))) void*)l, 16, 0, 0);
}

// sign-extended byte j (compile-time after unroll) of packed word w
__device__ __forceinline__ float sbyte_f(int w, int j) {
    return (float)((w << (24 - 8 * j)) >> 24);     // v_bfe_i32 + v_cvt_f32_i32
}

// ---------------- Pass 0: pack W1 into B-frag layout + zero bin cursors ----------
// W1pack[kc][t][lane][j] = W1[kc*32 + (lane>>4)*8 + j][t*16 + (lane&15)]
__global__ __launch_bounds__(256) void w1_pack(
    const float* __restrict__ W1, u16* __restrict__ w1p, int* __restrict__ cursor)
{
    if (blockIdx.x == 0 && threadIdx.x < 8) cursor[threadIdx.x] = 0;
    int w = blockIdx.x * 256 + threadIdx.x;   // 0..4095
    int lanep = w & 63, t = (w >> 6) & 7, kc = w >> 9;
    short8 o;
#pragma unroll
    for (int j = 0; j < 8; ++j) {
        int k = kc * 32 + (lanep >> 4) * 8 + j;
        int n = t * 16 + (lanep & 15);
        o[j] = (short)f2bf(W1[k * 128 + n]);
    }
    *(short8*)(w1p + (size_t)w * 8) = o;
}

// ---------------- Pass 1: dense GEMMs U = zs@W1a + b1, V = zt@W1b ----------------
// UNCHANGED from round 2 (int8 + per-row scale epilogue). A/B isolation: this
// round's change is edge binning only.
__global__ __launch_bounds__(256) void uv_gemm(
    const float* __restrict__ zs, const float* __restrict__ zt,
    const u16* __restrict__ w1p, const float* __restrict__ b1,
    char* __restrict__ U8, char* __restrict__ V8,
    float* __restrict__ su, float* __restrict__ sv,
    int M1, int M2, int nU)
{
    __shared__ u16 Alds[16384];   // 32 KB: 128 rows x 128 K (swizzled chunks)
    __shared__ u16 Blds[16384];   // 32 KB: 32 frags of this W1 half

    const int tid = threadIdx.x, wave = tid >> 6, lane = tid & 63;
    const int m15 = lane & 15, quad = lane >> 4;
    const bool isV = (int)blockIdx.x >= nU;
    const float* zsrc = isV ? zt : zs;
    char* dst = isV ? V8 : U8;
    float* sdst = isV ? sv : su;
    const int row0 = (isV ? ((int)blockIdx.x - nU) : (int)blockIdx.x) * 128;
    const int M = isV ? M2 : M1;
    const int nrows = (M - row0) < 128 ? (M - row0) : 128;

    const u16* wsrc = w1p + (isV ? 16384 : 0);
#pragma unroll
    for (int it = 0; it < 8; ++it) {
        int off = (wave * 8 + it) * 1024;
        ld_g2l16((const char*)wsrc + off + lane * 16, (char*)Blds + off);
    }

#pragma unroll
    for (int it = 0; it < 8; ++it) {
        int r = it * 16 + wave * 4 + (lane >> 4);
        int q = lane & 15;
        int c = q ^ (r & 15);                     // logical chunk to fetch
        int rr = r < nrows ? r : (nrows - 1);
        const float4* src = (const float4*)(zsrc + (size_t)(row0 + rr) * 128 + c * 8);
        float4 x = src[0], y = src[1];
        short8 o;
        o[0] = (short)f2bf(x.x); o[1] = (short)f2bf(x.y);
        o[2] = (short)f2bf(x.z); o[3] = (short)f2bf(x.w);
        o[4] = (short)f2bf(y.x); o[5] = (short)f2bf(y.y);
        o[6] = (short)f2bf(y.z); o[7] = (short)f2bf(y.w);
        *(short8*)((char*)Alds + r * 256 + q * 16) = o;
    }

    __builtin_amdgcn_s_waitcnt(0);
    __syncthreads();

    float4v acc[2][8];
#pragma unroll
    for (int a = 0; a < 2; ++a)
#pragma unroll
        for (int b = 0; b < 8; ++b)
            acc[a][b] = (float4v){0.f, 0.f, 0.f, 0.f};

#pragma unroll
    for (int kc = 0; kc < 4; ++kc) {
        short8 Af[2];
#pragma unroll
        for (int mtl = 0; mtl < 2; ++mtl) {
            int r = wave * 32 + mtl * 16 + m15;
            int c = kc * 4 + quad;
            int q = c ^ (r & 15);
            Af[mtl] = *(const short8*)((const char*)Alds + r * 256 + q * 16);
        }
#pragma unroll
        for (int t = 0; t < 8; ++t) {
            short8 Bf = *(const short8*)((const char*)Blds + (kc * 8 + t) * 1024 + lane * 16);
#pragma unroll
            for (int mtl = 0; mtl < 2; ++mtl)
                acc[mtl][t] = __builtin_amdgcn_mfma_f32_16x16x32_bf16(
                    Af[mtl], Bf, acc[mtl][t], 0, 0, 0);
        }
    }

    float b1v[8];
#pragma unroll
    for (int t = 0; t < 8; ++t) b1v[t] = isV ? 0.f : b1[t * 16 + m15];

#pragma unroll
    for (int mtl = 0; mtl < 2; ++mtl) {
#pragma unroll
        for (int r = 0; r < 4; ++r) {
            const int rr = wave * 32 + mtl * 16 + quad * 4 + r;
            float vals[8];
            float vmax = 0.f;
#pragma unroll
            for (int t = 0; t < 8; ++t) {
                float x = acc[mtl][t][r] + b1v[t];
                vals[t] = x;
                vmax = fmaxf(vmax, fabsf(x));
            }
            vmax = fmaxf(vmax, __shfl_xor(vmax, 1));
            vmax = fmaxf(vmax, __shfl_xor(vmax, 2));
            vmax = fmaxf(vmax, __shfl_xor(vmax, 4));
            vmax = fmaxf(vmax, __shfl_xor(vmax, 8));
            const float scl = vmax * (1.f / 127.f);
            const float rs = vmax > 0.f ? 127.f / vmax : 0.f;
            if (rr < nrows) {
                if (m15 == 0) sdst[row0 + rr] = scl;
#pragma unroll
                for (int t = 0; t < 8; ++t) {
                    int q = __float2int_rn(vals[t] * rs);
                    q = q > 127 ? 127 : (q < -127 ? -127 : q);
                    dst[(size_t)(row0 + rr) * 128 + t * 16 + m15] = (char)q;
                }
            }
        }
    }
}

// ---------------- Pass 2a: bin edges by U-row octant (XCD partitioning) ----------
// 8 bins of ~M1/8 rows (1.6 MB of U8 each — fits one XCD's 4 MB L2).
// Tuple = row | col<<17 | eid<<34 packed in u64 (guarded M1,M2<=128K, E<2^30).
// LDS-atomic ranks + one global atomicAdd per bin per block -> windowed writes.
__global__ __launch_bounds__(256) void edge_bin(
    const int* __restrict__ row, const int* __restrict__ col,
    u64* __restrict__ tup, int* __restrict__ cursor,
    int E, float binv, int C,
    const char* __restrict__ U8, const char* __restrict__ V8,
    const float* __restrict__ su, const float* __restrict__ sv,
    const float* __restrict__ W2, const float* __restrict__ b2,
    float* __restrict__ out)
{
    __shared__ int lcnt[8];
    __shared__ int lbase[8];
    const int tid = threadIdx.x;
    if (tid < 8) lcnt[tid] = 0;
    __syncthreads();
    const int eb = blockIdx.x * 4096;
    int rr[16], cc[16], bb[16], rk[16];
#pragma unroll
    for (int it = 0; it < 16; ++it) {
        int e = eb + it * 256 + tid;
        rk[it] = -1;
        if (e < E) {
            int r = row[e], c = col[e];
            int b = (int)((float)r * binv);
            b = b > 7 ? 7 : b;
            rr[it] = r; cc[it] = c; bb[it] = b;
            rk[it] = atomicAdd(&lcnt[b], 1);
        }
    }
    __syncthreads();
    if (tid < 8) lbase[tid] = atomicAdd(&cursor[tid], lcnt[tid]);
    __syncthreads();
#pragma unroll
    for (int it = 0; it < 16; ++it) {
        if (rk[it] < 0) continue;
        int e = eb + it * 256 + tid;
        int slot = lbase[bb[it]] + rk[it];
        if (slot < C) {
            tup[(size_t)bb[it] * C + slot] =
                (u64)(unsigned)rr[it] | ((u64)(unsigned)cc[it] << 17) | ((u64)(unsigned)e << 34);
        } else {
            // overflow slow path (statistically unreachable for ~uniform rows)
            float a = su[rr[it]], bs = sv[cc[it]];
            const signed char* up = (const signed char*)(U8 + (size_t)rr[it] * 128);
            const signed char* vp = (const signed char*)(V8 + (size_t)cc[it] * 128);
            float s = 0.f;
            for (int j = 0; j < 128; ++j) {
                float h = fmaf(a, (float)up[j], bs * (float)vp[j]);
                h = fmaxf(h, 0.f);
                s = fmaf(h, W2[j], s);
            }
            out[e] = s + b2[0];
        }
    }
}

// ---------------- Pass 2b: binned edge decode ------------------------------------
// blockIdx%8 = bin (= XCD under round-robin dispatch): each XCD's L2 keeps its
// 1.6 MB U-slab resident. 16 lanes/edge, 128 edges per chunk, grid-stride over
// chunks. Math identical to round 2 (same absmax).
__global__ __launch_bounds__(256) void edge_out(
    const char* __restrict__ U8, const char* __restrict__ V8,
    const float* __restrict__ su, const float* __restrict__ sv,
    const u64* __restrict__ tup, const int* __restrict__ cursor,
    const float* __restrict__ W2, const float* __restrict__ b2,
    float* __restrict__ out, int C, int chunks_per_bin)
{
    const int tid = threadIdx.x, m15 = tid & 15, g = tid >> 4;  // 16 groups
    const int bin = (int)blockIdx.x & 7;
    int chunk = (int)blockIdx.x >> 3;
    int cnt = cursor[bin];
    cnt = cnt < C ? cnt : C;
    float w2f[8];
#pragma unroll
    for (int j = 0; j < 8; ++j) w2f[j] = W2[m15 * 8 + j];
    const float b2v = b2[0];
    const u64* tb = tup + (size_t)bin * C;

    for (; chunk * 128 < cnt; chunk += chunks_per_bin) {
        const int base = chunk * 128;

        // Phase 1: tuple loads (8B broadcast within each 16-lane group).
        u64 t[8];
#pragma unroll
        for (int it = 0; it < 8; ++it) {
            int idx = base + it * 16 + g;
            t[it] = tb[idx < cnt ? idx : cnt - 1];
        }
        __builtin_amdgcn_sched_barrier(0);

        // Phase 2: payload gathers (8B int8 per lane per side) + scales.
        uint2 qu[8], qv[8];
        float fsu[8], fsv[8];
#pragma unroll
        for (int it = 0; it < 8; ++it) {
            int r = (int)(t[it] & 0x1FFFF);
            int c = (int)((t[it] >> 17) & 0x1FFFF);
            qu[it] = *(const uint2*)(U8 + (size_t)(unsigned)r * 128 + m15 * 8);
            qv[it] = *(const uint2*)(V8 + (size_t)(unsigned)c * 128 + m15 * 8);
            fsu[it] = su[r];
            fsv[it] = sv[c];
        }
        __builtin_amdgcn_sched_barrier(0);

        // Phase 3: dequant + relu + dot, consume in issue order.
#pragma unroll
        for (int it = 0; it < 8; ++it) {
            const float a = fsu[it], b = fsv[it];
            const int u0 = (int)qu[it].x, u1 = (int)qu[it].y;
            const int v0 = (int)qv[it].x, v1 = (int)qv[it].y;
            float s = 0.f;
#pragma unroll
            for (int j = 0; j < 4; ++j) {
                float h0 = fmaf(a, sbyte_f(u0, j), b * sbyte_f(v0, j));
                h0 = fmaxf(h0, 0.f);
                s = fmaf(h0, w2f[j], s);
                float h1 = fmaf(a, sbyte_f(u1, j), b * sbyte_f(v1, j));
                h1 = fmaxf(h1, 0.f);
                s = fmaf(h1, w2f[4 + j], s);
            }
            s += __shfl_xor(s, 1);
            s += __shfl_xor(s, 2);
            s += __shfl_xor(s, 4);
            s += __shfl_xor(s, 8);
            int idx = base + it * 16 + g;
            if (m15 == 0 && idx < cnt) out[(int)(t[it] >> 34)] = s + b2v;
        }
    }
}

// ---------------- Fallback (fp32, slow but correct) ------------------------------
__global__ __launch_bounds__(256) void edge_mlp_naive(
    const float* __restrict__ zs, const float* __restrict__ zt,
    const int* __restrict__ row, const int* __restrict__ col,
    const float* __restrict__ W1, const float* __restrict__ b1,
    const float* __restrict__ W2, const float* __restrict__ b2,
    float* __restrict__ out, int E)
{
    __shared__ float zr[4][256];
    int wave = threadIdx.x >> 6, lane = threadIdx.x & 63;
    int e = blockIdx.x * 4 + wave;
    int ec = e < E ? e : E - 1;
    const float* a = zs + (size_t)row[ec] * 128;
    const float* bb = zt + (size_t)col[ec] * 128;
    zr[wave][lane] = a[lane];
    zr[wave][64 + lane] = a[64 + lane];
    zr[wave][128 + lane] = bb[lane];
    zr[wave][192 + lane] = bb[64 + lane];
    __syncthreads();
    float h0 = b1[lane], h1 = b1[64 + lane];
    for (int k = 0; k < 256; ++k) {
        float zk = zr[wave][k];
        h0 = fmaf(zk, W1[k * 128 + lane], h0);
        h1 = fmaf(zk, W1[k * 128 + 64 + lane], h1);
    }
    h0 = h0 > 0.f ? h0 : 0.f;
    h1 = h1 > 0.f ? h1 : 0.f;
    float s = fmaf(h0, W2[lane], h1 * W2[64 + lane]);
    for (int m = 1; m < 64; m <<= 1) s += __shfl_xor(s, m);
    if (lane == 0 && e < E) out[e] = s + b2[0];
}

extern "C" void kernel_launch(void* const* d_in, const int* in_sizes, int n_in,
                              void* d_out, int out_size, void* d_ws, size_t ws_size,
                              hipStream_t stream) {
    const float* zs = (const float*)d_in[0];
    const float* zt = (const float*)d_in[1];
    const int*  row = (const int*)d_in[2];
    const int*  col = (const int*)d_in[3];
    const float* W1 = (const float*)d_in[4];
    const float* b1 = (const float*)d_in[5];
    const float* W2 = (const float*)d_in[6];
    const float* b2 = (const float*)d_in[7];
    float* out = (float*)d_out;

    const int nzs = in_sizes[0];       // 12,800,000 (100K x 128)
    const int nzt = in_sizes[1];       // 6,400,000  (50K x 128)
    const int E   = in_sizes[2];       // 1,000,000
    const int M1  = nzs / 128;
    const int M2  = nzt / 128;

    // per-bin tuple capacity: pow2 >= ~2x expected bin size
    int C = 65536;
    while (C < E / 4 + 1024) C <<= 1;  // 262144 for E=1M

    // ws layout: [tup 8*C u64][cursor 64B][su f32 M1][sv f32 M2][w1p 32K u16][U8][V8]
    const size_t tup_b = (size_t)8 * C * 8;
    const size_t need = tup_b + 64 + (size_t)M1 * 4 + (size_t)M2 * 4 + 65536
                      + (size_t)nzs + (size_t)nzt;
    const bool shapes_ok = (M1 <= 131072) && (M2 <= 131072) && (E > 0) && (E < (1 << 30));

    if (!shapes_ok || ws_size < need) {
        int nb = (E + 3) / 4;
        edge_mlp_naive<<<nb, 256, 0, stream>>>(zs, zt, row, col, W1, b1, W2, b2, out, E);
        return;
    }

    u64* tup    = (u64*)d_ws;
    int* cursor = (int*)((char*)d_ws + tup_b);
    float* su   = (float*)((char*)cursor + 64);
    float* sv   = su + M1;
    u16* w1p    = (u16*)(sv + M2);
    char* U8    = (char*)(w1p + 32768);
    char* V8    = U8 + (size_t)nzs;

    w1_pack<<<16, 256, 0, stream>>>(W1, w1p, cursor);

    const int nU = (M1 + 127) / 128;
    const int nV = (M2 + 127) / 128;
    uv_gemm<<<nU + nV, 256, 0, stream>>>(zs, zt, w1p, b1, U8, V8, su, sv, M1, M2, nU);

    const int rpb = (M1 + 7) / 8;
    const float binv = 1.0f / (float)rpb;
    edge_bin<<<(E + 4095) / 4096, 256, 0, stream>>>(
        row, col, tup, cursor, E, binv, C, U8, V8, su, sv, W2, b2, out);

    const int cpb = 1024;  // chunks (128 edges) per bin per sweep; grid-strided
    edge_out<<<8 * cpb, 256, 0, stream>>>(U8, V8, su, sv, tup, cursor, W2, b2, out, C, cpb);
}